// Round 2
// baseline (475.159 us; speedup 1.0000x reference)
//
#include <hip/hip_runtime.h>
#include <hip/hip_bf16.h>
#include <stdint.h>

#define Bsz 4096
#define Csz 10000
#define Dsz 256
#define BM 128   // B-dim tile (output rows)
#define BN 128   // C-dim tile (output cols)
#define BK 32
#define KST 40   // LDS row stride in bf16 elems: 80 B, 16B-aligned ds_read_b128, <=2-way banks

typedef __attribute__((ext_vector_type(8))) __bf16 bf16x8;  // matches gfx950 mfma builtin signature
typedef __attribute__((ext_vector_type(4))) float f32x4;

__device__ __forceinline__ unsigned int f2bf(float x) {
    // round-to-nearest-even fp32 -> bf16 (finite normals; no NaN path needed)
    unsigned int u = __float_as_uint(x);
    return (u + 0x7fffu + ((u >> 16) & 1u)) >> 16;
}
__device__ __forceinline__ unsigned int pack2(float a, float b) {
    return f2bf(a) | (f2bf(b) << 16);
}

// ---- kernel 1: fused fp32->bf16 convert + row sq-norms; zero likelihood slot ----
// one wave per row (256 floats = 64 lanes x float4)
__global__ __launch_bounds__(256) void conv_kernel(
        const float* __restrict__ feat, const float* __restrict__ centers,
        unsigned short* __restrict__ featB, unsigned short* __restrict__ centB,
        float* __restrict__ fsq, float* __restrict__ csq,
        float* __restrict__ like_out) {
    if (blockIdx.x == 0 && threadIdx.x == 0) *like_out = 0.f;
    int row  = blockIdx.x * 4 + (threadIdx.x >> 6);
    int lane = threadIdx.x & 63;
    if (row >= Bsz + Csz) return;
    const float* src;
    unsigned short* dst;
    float* nrm;
    if (row < Bsz) { src = feat + (size_t)row * Dsz; dst = featB + (size_t)row * Dsz; nrm = fsq + row; }
    else { int r = row - Bsz; src = centers + (size_t)r * Dsz; dst = centB + (size_t)r * Dsz; nrm = csq + r; }
    float4 v = *(const float4*)(src + lane * 4);
    *(uint2*)(dst + lane * 4) = make_uint2(pack2(v.x, v.y), pack2(v.z, v.w));
    float s = v.x * v.x + v.y * v.y + v.z * v.z + v.w * v.w;
    #pragma unroll
    for (int o = 32; o > 0; o >>= 1) s += __shfl_down(s, o);
    if (lane == 0) *nrm = s;
}

// ---- kernel 2: likelihood = sum_b ||feat[b]-centers[label[b]]||^2 / (2B) ----
__global__ __launch_bounds__(256) void like_kernel(
        const float* __restrict__ feat, const float* __restrict__ centers,
        const int* __restrict__ label, float* __restrict__ like_out) {
    int row  = blockIdx.x * 4 + (threadIdx.x >> 6);
    int lane = threadIdx.x & 63;
    int lb = label[row];
    float4 f = *(const float4*)(feat + (size_t)row * Dsz + lane * 4);
    float4 c = *(const float4*)(centers + (size_t)lb * Dsz + lane * 4);
    float dx = f.x - c.x, dy = f.y - c.y, dz = f.z - c.z, dw = f.w - c.w;
    float s = dx * dx + dy * dy + dz * dz + dw * dw;
    #pragma unroll
    for (int o = 32; o > 0; o >>= 1) s += __shfl_down(s, o);
    if (lane == 0) atomicAdd(like_out, s * (1.0f / (2.0f * Bsz)));
}

// ---- kernel 3: fused GEMM + logits/margin epilogue ----
// A-operand = centers tile (M = C dim), B-operand = feat tile (N = B dim):
// D[row=quad*4+reg -> c_local][col=lane&15 -> b_local], so each lane's f32x4
// holds 4 CONSECUTIVE c -> float4 stores along the C-contiguous output.
__global__ __launch_bounds__(256) void lgm_gemm_kernel(
        const unsigned short* __restrict__ featB, const unsigned short* __restrict__ centB,
        const int* __restrict__ label, const float* __restrict__ fsq,
        const float* __restrict__ csq, float* __restrict__ out) {
    __shared__ unsigned short As[BN * KST];  // centers tile [c_local][k]
    __shared__ unsigned short Bs[BM * KST];  // feat tile    [b_local][k]
    __shared__ float Fs[BM];
    __shared__ float Cq[BN];
    __shared__ int   Lb[BM];

    const int tid     = threadIdx.x;
    const int rowBase = blockIdx.y * BM;   // B rows: 4096 % 128 == 0
    const int colBase = blockIdx.x * BN;   // C cols: last tile partially valid

    if (tid < 128) {
        Fs[tid] = fsq[rowBase + tid];
        Lb[tid] = label[rowBase + tid];
        int c = colBase + tid;
        Cq[tid] = (c < Csz) ? csq[c] : 0.f;
    }

    const int lane = tid & 63;
    const int wv   = tid >> 6;
    const int wvC  = (wv & 1) * 64;    // wave offset along C (MFMA M)
    const int wvB  = (wv >> 1) * 64;   // wave offset along B (MFMA N)
    const int quad = lane >> 4;
    const int l15  = lane & 15;

    f32x4 acc[4][4];
    #pragma unroll
    for (int i = 0; i < 4; ++i)
        #pragma unroll
        for (int j = 0; j < 4; ++j)
            acc[i][j] = (f32x4){0.f, 0.f, 0.f, 0.f};

    const int srow = tid >> 2;   // 0..63 staging row
    const int schk = tid & 3;    // 16B chunk within the 64B k-slab

    for (int k0 = 0; k0 < Dsz; k0 += BK) {
        __syncthreads();
        #pragma unroll
        for (int rr = 0; rr < 128; rr += 64) {
            int r = srow + rr;
            int crow = colBase + r; if (crow >= Csz) crow = Csz - 1;  // clamp; stores masked
            *(uint4*)(As + r * KST + schk * 8) =
                *(const uint4*)(centB + (size_t)crow * Dsz + k0 + schk * 8);
            *(uint4*)(Bs + r * KST + schk * 8) =
                *(const uint4*)(featB + (size_t)(rowBase + r) * Dsz + k0 + schk * 8);
        }
        __syncthreads();

        bf16x8 af[4], bfr[4];
        #pragma unroll
        for (int mi = 0; mi < 4; ++mi)
            af[mi] = *(const bf16x8*)(As + (wvC + mi * 16 + l15) * KST + quad * 8);
        #pragma unroll
        for (int ni = 0; ni < 4; ++ni)
            bfr[ni] = *(const bf16x8*)(Bs + (wvB + ni * 16 + l15) * KST + quad * 8);
        #pragma unroll
        for (int mi = 0; mi < 4; ++mi)
            #pragma unroll
            for (int ni = 0; ni < 4; ++ni)
                acc[mi][ni] = __builtin_amdgcn_mfma_f32_16x16x32_bf16(
                    af[mi], bfr[ni], acc[mi][ni], 0, 0, 0);
    }

    float* outL = out;
    float* outM = out + (size_t)Bsz * Csz;
    #pragma unroll
    for (int mi = 0; mi < 4; ++mi) {
        const int cT0 = wvC + mi * 16 + quad * 4;   // local c of this lane's float4
        const int gcb = colBase + cT0;
        const bool valid = (gcb + 3 < Csz);         // Csz%4==0 -> float4-granular guard
        const float4 cq = *(const float4*)&Cq[cT0];
        #pragma unroll
        for (int ni = 0; ni < 4; ++ni) {
            const int bL = wvB + ni * 16 + l15;
            const int gb = rowBase + bL;
            const float fs = Fs[bL];
            const int   lb = Lb[bL];
            f32x4 a = acc[mi][ni];
            float4 lg, mg;
            lg.x = a[0] - 0.5f * (fs + cq.x);
            lg.y = a[1] - 0.5f * (fs + cq.y);
            lg.z = a[2] - 0.5f * (fs + cq.z);
            lg.w = a[3] - 0.5f * (fs + cq.w);
            mg.x = (gcb + 0 == lb) ? lg.x * 1.1f : lg.x;
            mg.y = (gcb + 1 == lb) ? lg.y * 1.1f : lg.y;
            mg.z = (gcb + 2 == lb) ? lg.z * 1.1f : lg.z;
            mg.w = (gcb + 3 == lb) ? lg.w * 1.1f : lg.w;
            if (valid) {
                size_t off = (size_t)gb * Csz + gcb;
                *(float4*)(outL + off) = lg;
                *(float4*)(outM + off) = mg;
            }
        }
    }
}

extern "C" void kernel_launch(void* const* d_in, const int* in_sizes, int n_in,
                              void* d_out, int out_size, void* d_ws, size_t ws_size,
                              hipStream_t stream) {
    const float* feat    = (const float*)d_in[0];
    const int*   label   = (const int*)d_in[1];
    const float* centers = (const float*)d_in[2];
    float* out = (float*)d_out;

    unsigned short* featB = (unsigned short*)d_ws;                 // [4096*256] bf16
    unsigned short* centB = featB + (size_t)Bsz * Dsz;             // [10000*256] bf16
    float* fsq = (float*)(centB + (size_t)Csz * Dsz);              // [4096]
    float* csq = fsq + Bsz;                                        // [10000]
    float* like_out = out + (size_t)2 * Bsz * Csz;

    conv_kernel<<<dim3((Bsz + Csz + 3) / 4), 256, 0, stream>>>(
        feat, centers, featB, centB, fsq, csq, like_out);
    like_kernel<<<dim3(Bsz / 4), 256, 0, stream>>>(feat, centers, label, like_out);
    lgm_gemm_kernel<<<dim3((Csz + BN - 1) / BN, Bsz / BM), 256, 0, stream>>>(
        featB, centB, label, fsq, csq, out);
}